// Round 11
// baseline (406.353 us; speedup 1.0000x reference)
//
#include <hip/hip_runtime.h>

// AUGRU, round 11: producer/consumer overlap with RIGHT-SIZED LDS (R10 fix).
//  R10's 84KB LDS pad throttled the 640 producer blocks to 1/CU -> producer-
//  bound 405us. Now LDS = 20,992B (what rec actually uses), so producers pack
//  2+/CU and finish ~50us, hidden under rec. Rec blocks 0..63 are dispatched
//  to distinct CUs anyway; independent producer waves sharing a rec CU fill
//  idle issue slots (m114), they are not lockstep-coupled.
//  Blocks 0..63   : persistent recurrence (R9 structure, proven).
//  Blocks 64..703 : xproj producers; (c,bblk) -> flag[c*64+bblk] release.
// Fallback: proven single-kernel (R2) if ws too small.

#define T_N   200
#define I_DIM 128
#define H_DIM 128
#define NBLK  64
#define CHUNK_T  20
#define NCHUNK   10                 // 200/20
#define XBLK     (NBLK * NCHUNK)    // 640 producer blocks

typedef float  f32x4  __attribute__((ext_vector_type(4)));
typedef __bf16 bf16x4 __attribute__((ext_vector_type(4)));
typedef __bf16 bf16x8 __attribute__((ext_vector_type(8)));

// preact layout: ((t*NBLK+bblk)*3 + g)*4096 + hidgrp*128 + b*8  (R9 layout)
#define GATE_BYTES 4096
#define PB_BYTES   (3 * GATE_BYTES)
#define PRE_BYTES  ((size_t)T_N * NBLK * PB_BYTES)   // 157,286,400
#define FLAG_BYTES 4096

// rec LDS: lds_h 4096 + lds_rh 4096 + lds_att 12800 = 20992 bytes
#define LDS_TOTAL 20992

// fallback LDS
#define LDA_STRIDE 264
#define LATT_STRIDE 201

__device__ __forceinline__ float fast_sigmoid(float x) {
  float e = __builtin_amdgcn_exp2f(-1.4426950408889634f * x);
  return __builtin_amdgcn_rcpf(1.0f + e);
}
__device__ __forceinline__ float fast_tanh(float x) {
  float e = __builtin_amdgcn_exp2f(2.8853900817779268f * x);
  return 1.0f - 2.0f * __builtin_amdgcn_rcpf(1.0f + e);
}
__device__ __forceinline__ void barrier_lds() {
  asm volatile("s_waitcnt lgkmcnt(0)\n\ts_barrier" ::: "memory");
}
__device__ __forceinline__ bf16x8 pack8(float4 a, float4 b) {
  bf16x8 t;
  t[0] = (__bf16)a.x; t[1] = (__bf16)a.y; t[2] = (__bf16)a.z; t[3] = (__bf16)a.w;
  t[4] = (__bf16)b.x; t[5] = (__bf16)b.y; t[6] = (__bf16)b.z; t[7] = (__bf16)b.w;
  return t;
}
__device__ __forceinline__ int swz(int row, int bytecol) {
  return row * 256 + (bytecol ^ ((row & 7) << 4));
}
__device__ __forceinline__ void wait_flag(const int* f) {
  while (__hip_atomic_load(f, __ATOMIC_ACQUIRE, __HIP_MEMORY_SCOPE_AGENT) == 0) {
    __builtin_amdgcn_s_sleep(8);
  }
}

// ---------------------------------------------------------------------------
// Fused kernel: grid = 64 rec blocks + 640 xproj blocks, 512 threads.
// ---------------------------------------------------------------------------
__global__ __launch_bounds__(512, 1)
void augru_pipe_kernel(const float* __restrict__ inputs,
                       const float* __restrict__ attn,
                       const float* __restrict__ Wz, const float* __restrict__ bz,
                       const float* __restrict__ Wr, const float* __restrict__ br,
                       const float* __restrict__ Wh, const float* __restrict__ bh,
                       float* __restrict__ out,
                       char* __restrict__ pre, int* __restrict__ flags) {
  __shared__ __align__(16) char lds_all[LDS_TOTAL];

  const int tid = threadIdx.x;
  const int l   = tid & 63;
  const int l15 = l & 15;
  const int lk  = l >> 4;

  if (blockIdx.x >= NBLK) {
    // =================== producer: xproj chunk ===================
    const int bidp = blockIdx.x - NBLK;
    const int bblk = bidp & (NBLK - 1);
    const int c    = bidp >> 6;            // chunk 0..9
    const int w8   = tid >> 6;             // 0..7
    const int half = w8 >> 2;              // 0,1 -> t-halves
    const int w    = w8 & 3;               // role within half
    const int t0   = c * CHUNK_T + half * (CHUNK_T / 2);
    const int r0   = bblk * 16;

    // A-frags: W x-part (k=0..127). slot s: gate g=s>>1, hid0=w*32+(s&1)*16.
    bf16x8 wb[24];
    f32x4  bias4[6];
    #pragma unroll
    for (int s = 0; s < 6; ++s) {
      int hid0 = w * 32 + (s & 1) * 16;
      const float* Wp; const float* bp;
      if (s < 2)      { Wp = Wz; bp = bz; }
      else if (s < 4) { Wp = Wr; bp = br; }
      else            { Wp = Wh; bp = bh; }
      float4 bv = *(const float4*)&bp[hid0 + lk * 4];
      bias4[s][0] = bv.x; bias4[s][1] = bv.y; bias4[s][2] = bv.z; bias4[s][3] = bv.w;
      const float* Wrow = Wp + (size_t)(hid0 + l15) * 256;
      #pragma unroll
      for (int kt = 0; kt < 4; ++kt) {
        const float* p = Wrow + kt * 32 + lk * 8;
        wb[s * 4 + kt] = pack8(*(const float4*)p, *(const float4*)(p + 4));
      }
    }

    const float* xbase = inputs + (size_t)(r0 + l15) * (T_N * I_DIM);

    #pragma unroll 2
    for (int ti = 0; ti < CHUNK_T / 2; ++ti) {
      const int t = t0 + ti;
      bf16x8 xf[4];
      #pragma unroll
      for (int kt = 0; kt < 4; ++kt) {
        const float* p = xbase + (size_t)t * I_DIM + kt * 32 + lk * 8;
        xf[kt] = pack8(*(const float4*)p, *(const float4*)(p + 4));
      }
      f32x4 acc[6];
      #pragma unroll
      for (int s = 0; s < 6; ++s) acc[s] = bias4[s];
      #pragma unroll
      for (int kt = 0; kt < 4; ++kt)
        #pragma unroll
        for (int s = 0; s < 6; ++s)
          acc[s] = __builtin_amdgcn_mfma_f32_16x16x32_bf16(wb[s * 4 + kt], xf[kt], acc[s], 0, 0, 0);

      char* base = pre + ((size_t)t * NBLK + bblk) * PB_BYTES;
      #pragma unroll
      for (int s = 0; s < 6; ++s) {
        int g      = s >> 1;
        int hidgrp = w * 8 + (s & 1) * 4 + lk;
        bf16x4 v;
        v[0] = (__bf16)acc[s][0]; v[1] = (__bf16)acc[s][1];
        v[2] = (__bf16)acc[s][2]; v[3] = (__bf16)acc[s][3];
        *(bf16x4*)(base + g * GATE_BYTES + hidgrp * 128 + l15 * 8) = v;
      }
    }

    __syncthreads();          // both halves done
    __threadfence();          // stores visible at agent scope
    if (tid == 0)
      __hip_atomic_store(&flags[c * NBLK + bblk], 1, __ATOMIC_RELEASE, __HIP_MEMORY_SCOPE_AGENT);
    return;
  }

  // =================== consumer: recurrence (R9 structure) ===================
  short* lds_h  = (short*)lds_all;             // [16][128] bf16, swizzled
  short* lds_rh = (short*)(lds_all + 4096);    // [16][128] bf16, swizzled
  float* lds_att = (float*)(lds_all + 8192);   // [t][16]

  const int w     = tid >> 6;
  const int r0    = blockIdx.x * 16;
  const int myhid = w * 16 + lk * 4;

  for (int idx = tid; idx < T_N * 16; idx += 512) {
    int t = idx >> 4, b = idx & 15;
    lds_att[idx] = attn[(size_t)(r0 + b) * T_N + t];
  }
  for (int idx = tid; idx < 16 * 128; idx += 512) lds_h[idx] = 0;

  bf16x8 wzH[4], wrH[4], whH[4];
  {
    const float* pz = Wz + (size_t)(w * 16 + l15) * 256 + 128;
    const float* pr = Wr + (size_t)(w * 16 + l15) * 256 + 128;
    const float* ph = Wh + (size_t)(w * 16 + l15) * 256 + 128;
    #pragma unroll
    for (int kt = 0; kt < 4; ++kt) {
      const float* a = pz + kt * 32 + lk * 8;
      wzH[kt] = pack8(*(const float4*)a, *(const float4*)(a + 4));
      const float* b = pr + kt * 32 + lk * 8;
      wrH[kt] = pack8(*(const float4*)b, *(const float4*)(b + 4));
      const float* cc = ph + kt * 32 + lk * 8;
      whH[kt] = pack8(*(const float4*)cc, *(const float4*)(cc + 4));
    }
  }

  float hreg[4];
  #pragma unroll
  for (int q = 0; q < 4; ++q) hreg[q] = 0.0f;

  const char* pb = pre + (size_t)blockIdx.x * PB_BYTES + (w * 4 + lk) * 128 + l15 * 8;
  const size_t tstride = (size_t)NBLK * PB_BYTES;

  // wait for chunk 0 (covers t=0,1 prologue loads)
  wait_flag(&flags[0 * NBLK + blockIdx.x]);

  bf16x4 pf[2][3];
  #pragma unroll
  for (int d = 0; d < 2; ++d)
    #pragma unroll
    for (int g = 0; g < 3; ++g)
      pf[d][g] = *(const bf16x4*)(pb + d * tstride + g * GATE_BYTES);

  const int wr_off = swz(l15, 32 * w + 8 * lk);

  __syncthreads();

  #pragma unroll 2
  for (int t = 0; t < T_N; ++t) {
    float pzv[4], prv[4], phv[4];
    #pragma unroll
    for (int q = 0; q < 4; ++q) {
      pzv[q] = (float)pf[t & 1][0][q];
      prv[q] = (float)pf[t & 1][1][q];
      phv[q] = (float)pf[t & 1][2][q];
    }
    if (t + 2 < T_N) {
      if (((t + 2) % CHUNK_T) == 0)
        wait_flag(&flags[((t + 2) / CHUNK_T) * NBLK + blockIdx.x]);
      const char* b = pb + (size_t)(t + 2) * tstride;
      #pragma unroll
      for (int g = 0; g < 3; ++g)
        pf[t & 1][g] = *(const bf16x4*)(b + g * GATE_BYTES);
    }

    bf16x8 hb[4];
    #pragma unroll
    for (int kt = 0; kt < 4; ++kt)
      hb[kt] = *(const bf16x8*)((const char*)lds_h + swz(l15, kt * 64 + lk * 16));
    const float av = lds_att[t * 16 + l15];

    f32x4 zA, zB, rA, rB;
    { f32x4 a; a[0]=pzv[0]; a[1]=pzv[1]; a[2]=pzv[2]; a[3]=pzv[3]; zA = a; }
    { f32x4 a; a[0]=prv[0]; a[1]=prv[1]; a[2]=prv[2]; a[3]=prv[3]; rA = a; }
    { f32x4 z; z[0]=0.f; z[1]=0.f; z[2]=0.f; z[3]=0.f; zB = z; rB = z; }
    zA = __builtin_amdgcn_mfma_f32_16x16x32_bf16(wzH[0], hb[0], zA, 0, 0, 0);
    rA = __builtin_amdgcn_mfma_f32_16x16x32_bf16(wrH[0], hb[0], rA, 0, 0, 0);
    zB = __builtin_amdgcn_mfma_f32_16x16x32_bf16(wzH[1], hb[1], zB, 0, 0, 0);
    rB = __builtin_amdgcn_mfma_f32_16x16x32_bf16(wrH[1], hb[1], rB, 0, 0, 0);
    zA = __builtin_amdgcn_mfma_f32_16x16x32_bf16(wzH[2], hb[2], zA, 0, 0, 0);
    rA = __builtin_amdgcn_mfma_f32_16x16x32_bf16(wrH[2], hb[2], rA, 0, 0, 0);
    zB = __builtin_amdgcn_mfma_f32_16x16x32_bf16(wzH[3], hb[3], zB, 0, 0, 0);
    rB = __builtin_amdgcn_mfma_f32_16x16x32_bf16(wrH[3], hb[3], rB, 0, 0, 0);

    bf16x4 rhv;
    #pragma unroll
    for (int q = 0; q < 4; ++q) {
      float rr = fast_sigmoid(rA[q] + rB[q]);
      rhv[q] = (__bf16)(rr * hreg[q]);
    }
    *(bf16x4*)((char*)lds_rh + wr_off) = rhv;
    float zp[4];
    #pragma unroll
    for (int q = 0; q < 4; ++q)
      zp[q] = av * fast_sigmoid(zA[q] + zB[q]);
    barrier_lds();

    bf16x8 rb[4];
    #pragma unroll
    for (int kt = 0; kt < 4; ++kt)
      rb[kt] = *(const bf16x8*)((const char*)lds_rh + swz(l15, kt * 64 + lk * 16));
    f32x4 hA, hB;
    { f32x4 a; a[0]=phv[0]; a[1]=phv[1]; a[2]=phv[2]; a[3]=phv[3]; hA = a; }
    { f32x4 z; z[0]=0.f; z[1]=0.f; z[2]=0.f; z[3]=0.f; hB = z; }
    hA = __builtin_amdgcn_mfma_f32_16x16x32_bf16(whH[0], rb[0], hA, 0, 0, 0);
    hB = __builtin_amdgcn_mfma_f32_16x16x32_bf16(whH[1], rb[1], hB, 0, 0, 0);
    hA = __builtin_amdgcn_mfma_f32_16x16x32_bf16(whH[2], rb[2], hA, 0, 0, 0);
    hB = __builtin_amdgcn_mfma_f32_16x16x32_bf16(whH[3], rb[3], hB, 0, 0, 0);

    bf16x4 hbv;
    #pragma unroll
    for (int q = 0; q < 4; ++q) {
      float ht = fast_tanh(hA[q] + hB[q]);
      float hn = __builtin_fmaf(zp[q], ht - hreg[q], hreg[q]);
      hreg[q] = hn;
      hbv[q] = (__bf16)hn;
    }
    *(bf16x4*)((char*)lds_h + wr_off) = hbv;
    barrier_lds();
  }

  float4 o;
  o.x = hreg[0]; o.y = hreg[1]; o.z = hreg[2]; o.w = hreg[3];
  *(float4*)&out[(size_t)(r0 + l15) * H_DIM + myhid] = o;
}

// ---------------------------------------------------------------------------
// Fallback: proven single-kernel version (round 2, 410 us).
// ---------------------------------------------------------------------------
__global__ __launch_bounds__(256, 1)
void augru_kernel(const float* __restrict__ inputs,
                  const float* __restrict__ attn,
                  const float* __restrict__ Wz, const float* __restrict__ bz,
                  const float* __restrict__ Wr, const float* __restrict__ br,
                  const float* __restrict__ Wh, const float* __restrict__ bh,
                  float* __restrict__ out) {
  __shared__ __align__(16) short lds_a[16 * LDA_STRIDE];
  __shared__ float lds_att[16 * LATT_STRIDE];

  const int tid = threadIdx.x;
  const int w   = tid >> 6;
  const int l   = tid & 63;
  const int l15 = l & 15;
  const int lk  = l >> 4;
  const int r0  = blockIdx.x * 16;

  for (int idx = tid; idx < 16 * T_N; idx += 256) {
    int row = idx / T_N, t = idx - row * T_N;
    lds_att[row * LATT_STRIDE + t] = attn[(size_t)(r0 + row) * T_N + t];
  }
  for (int idx = tid; idx < 16 * H_DIM; idx += 256) {
    int row = idx >> 7, c = idx & 127;
    lds_a[row * LDA_STRIDE + c] = 0;
  }

  bf16x8 w1[32];
  float  bias1[4];
  #pragma unroll
  for (int ct = 0; ct < 4; ++ct) {
    int n = w * 32 + (ct & 1) * 16 + l15;
    const float* Wp; float bv;
    if (ct < 2) { Wp = Wz + (size_t)n * 256; bv = bz[n]; }
    else        { Wp = Wr + (size_t)n * 256; bv = br[n]; }
    bias1[ct] = bv;
    #pragma unroll
    for (int kt = 0; kt < 8; ++kt) {
      const float* p = Wp + kt * 32 + lk * 8;
      w1[ct * 8 + kt] = pack8(*(const float4*)p, *(const float4*)(p + 4));
    }
  }
  bf16x8 w2[16];
  float  bias2[2];
  #pragma unroll
  for (int ct = 0; ct < 2; ++ct) {
    int n = w * 32 + ct * 16 + l15;
    bias2[ct] = bh[n];
    const float* Wp = Wh + (size_t)n * 256;
    #pragma unroll
    for (int kt = 0; kt < 8; ++kt) {
      const float* p = Wp + kt * 32 + lk * 8;
      w2[ct * 8 + kt] = pack8(*(const float4*)p, *(const float4*)(p + 4));
    }
  }

  float hreg[2][4];
  #pragma unroll
  for (int ct = 0; ct < 2; ++ct)
    #pragma unroll
    for (int q = 0; q < 4; ++q) hreg[ct][q] = 0.0f;

  const float* xbase = inputs + (size_t)(r0 + l15) * (T_N * I_DIM);
  bf16x8 xfrag[4];
  #pragma unroll
  for (int kt = 0; kt < 4; ++kt) {
    const float* p = xbase + kt * 32 + lk * 8;
    xfrag[kt] = pack8(*(const float4*)p, *(const float4*)(p + 4));
  }

  __syncthreads();

  float4 xr0[4], xr1[4];
  for (int t = 0; t < T_N; ++t) {
    if (t + 1 < T_N) {
      #pragma unroll
      for (int kt = 0; kt < 4; ++kt) {
        const float* p = xbase + (size_t)(t + 1) * I_DIM + kt * 32 + lk * 8;
        xr0[kt] = *(const float4*)p;
        xr1[kt] = *(const float4*)(p + 4);
      }
    }
    bf16x8 hfrag[4];
    #pragma unroll
    for (int kt = 0; kt < 4; ++kt)
      hfrag[kt] = *(const bf16x8*)&lds_a[l15 * LDA_STRIDE + kt * 32 + lk * 8];
    float av[4];
    #pragma unroll
    for (int q = 0; q < 4; ++q) av[q] = lds_att[(lk * 4 + q) * LATT_STRIDE + t];

    f32x4 acc[4];
    #pragma unroll
    for (int ct = 0; ct < 4; ++ct) {
      f32x4 a; a[0] = bias1[ct]; a[1] = bias1[ct]; a[2] = bias1[ct]; a[3] = bias1[ct];
      acc[ct] = a;
    }
    #pragma unroll
    for (int kt = 0; kt < 4; ++kt)
      #pragma unroll
      for (int ct = 0; ct < 4; ++ct)
        acc[ct] = __builtin_amdgcn_mfma_f32_16x16x32_bf16(xfrag[kt], w1[ct * 8 + kt], acc[ct], 0, 0, 0);

    f32x4 acc2[2];
    #pragma unroll
    for (int ct = 0; ct < 2; ++ct) {
      f32x4 a; a[0] = bias2[ct]; a[1] = bias2[ct]; a[2] = bias2[ct]; a[3] = bias2[ct];
      acc2[ct] = a;
    }
    #pragma unroll
    for (int kt = 0; kt < 4; ++kt)
      #pragma unroll
      for (int ct = 0; ct < 2; ++ct)
        acc2[ct] = __builtin_amdgcn_mfma_f32_16x16x32_bf16(xfrag[kt], w2[ct * 8 + kt], acc2[ct], 0, 0, 0);

    #pragma unroll
    for (int kt = 0; kt < 4; ++kt)
      #pragma unroll
      for (int ct = 0; ct < 4; ++ct)
        acc[ct] = __builtin_amdgcn_mfma_f32_16x16x32_bf16(hfrag[kt], w1[ct * 8 + 4 + kt], acc[ct], 0, 0, 0);

    float zp[2][4];
    #pragma unroll
    for (int ct = 0; ct < 2; ++ct) {
      int col = w * 32 + ct * 16 + l15;
      #pragma unroll
      for (int q = 0; q < 4; ++q) {
        int row = lk * 4 + q;
        zp[ct][q] = av[q] * fast_sigmoid(acc[ct][q]);
        float rr = fast_sigmoid(acc[2 + ct][q]);
        __bf16 rhb = (__bf16)(rr * hreg[ct][q]);
        lds_a[row * LDA_STRIDE + 128 + col] = __builtin_bit_cast(short, rhb);
      }
    }
    barrier_lds();

    bf16x8 rfrag[4];
    #pragma unroll
    for (int kt = 0; kt < 4; ++kt)
      rfrag[kt] = *(const bf16x8*)&lds_a[l15 * LDA_STRIDE + 128 + kt * 32 + lk * 8];
    #pragma unroll
    for (int kt = 0; kt < 4; ++kt)
      #pragma unroll
      for (int ct = 0; ct < 2; ++ct)
        acc2[ct] = __builtin_amdgcn_mfma_f32_16x16x32_bf16(rfrag[kt], w2[ct * 8 + 4 + kt], acc2[ct], 0, 0, 0);

    if (t + 1 < T_N) {
      #pragma unroll
      for (int kt = 0; kt < 4; ++kt)
        xfrag[kt] = pack8(xr0[kt], xr1[kt]);
    }

    #pragma unroll
    for (int ct = 0; ct < 2; ++ct) {
      int col = w * 32 + ct * 16 + l15;
      #pragma unroll
      for (int q = 0; q < 4; ++q) {
        int row = lk * 4 + q;
        float ht = fast_tanh(acc2[ct][q]);
        float ho = hreg[ct][q];
        float hn = __builtin_fmaf(zp[ct][q], ht - ho, ho);
        hreg[ct][q] = hn;
        __bf16 hb = (__bf16)hn;
        lds_a[row * LDA_STRIDE + col] = __builtin_bit_cast(short, hb);
      }
    }
    barrier_lds();
  }

  #pragma unroll
  for (int ct = 0; ct < 2; ++ct) {
    int col = w * 32 + ct * 16 + l15;
    #pragma unroll
    for (int q = 0; q < 4; ++q) {
      int row = lk * 4 + q;
      out[(size_t)(r0 + row) * H_DIM + col] = hreg[ct][q];
    }
  }
}

extern "C" void kernel_launch(void* const* d_in, const int* in_sizes, int n_in,
                              void* d_out, int out_size, void* d_ws, size_t ws_size,
                              hipStream_t stream) {
  (void)in_sizes; (void)n_in; (void)out_size;
  const float* inputs = (const float*)d_in[0];
  const float* attn   = (const float*)d_in[1];
  const float* Wz     = (const float*)d_in[2];
  const float* bz     = (const float*)d_in[3];
  const float* Wr     = (const float*)d_in[4];
  const float* br     = (const float*)d_in[5];
  const float* Wh     = (const float*)d_in[6];
  const float* bh     = (const float*)d_in[7];
  float* out = (float*)d_out;

  if (ws_size >= PRE_BYTES + FLAG_BYTES) {
    char* pre   = (char*)d_ws;
    int*  flags = (int*)(pre + PRE_BYTES);
    hipMemsetAsync(flags, 0, NCHUNK * NBLK * sizeof(int), stream);
    augru_pipe_kernel<<<NBLK + XBLK, 512, 0, stream>>>(
        inputs, attn, Wz, bz, Wr, br, Wh, bh, out, pre, flags);
  } else {
    augru_kernel<<<NBLK, 256, 0, stream>>>(inputs, attn, Wz, bz, Wr, br, Wh, bh, out);
  }
}

// Round 12
// 236.043 us; speedup vs baseline: 1.7215x; 1.7215x over previous
//
#include <hip/hip_runtime.h>

// AUGRU, round 12: two-pass (R9 structure), xproj rebuilt with cooperative
// LDS-staged x (coalesced, deduplicated, double-buffered).
//  Pass 1 (xproj): 512 blocks x 256 thr, TCHUNK=25. Per t: coop-load 16x128
//     f32 x-tile (coalesced 512B rows), pack->bf16 once, XOR-swizzled LDS,
//     waves ds_read_b128 frags; D[hid][batch] = Wx(A) x x^T(B) + bias;
//     preacts bf16 -> [t][bblk][gate][hidgrp32][batch16 x 8B] (coalesced).
//  Pass 2 (rec): VERBATIM R9 (measured 177 us).
// Fallback: proven single-kernel (R2) if ws too small.

#define T_N   200
#define I_DIM 128
#define H_DIM 128
#define NBLK  64
#define TCHUNK 25

typedef float  f32x4  __attribute__((ext_vector_type(4)));
typedef __bf16 bf16x4 __attribute__((ext_vector_type(4)));
typedef __bf16 bf16x8 __attribute__((ext_vector_type(8)));

// preact layout: ((t*NBLK+bblk)*3 + g)*4096 + hidgrp*128 + b*8
#define GATE_BYTES 4096
#define PB_BYTES   (3 * GATE_BYTES)
#define PRE_BYTES  ((size_t)T_N * NBLK * PB_BYTES)   // 157,286,400

// fallback LDS
#define LDA_STRIDE 264
#define LATT_STRIDE 201

__device__ __forceinline__ float fast_sigmoid(float x) {
  float e = __builtin_amdgcn_exp2f(-1.4426950408889634f * x);
  return __builtin_amdgcn_rcpf(1.0f + e);
}
__device__ __forceinline__ float fast_tanh(float x) {
  float e = __builtin_amdgcn_exp2f(2.8853900817779268f * x);
  return 1.0f - 2.0f * __builtin_amdgcn_rcpf(1.0f + e);
}
__device__ __forceinline__ void barrier_lds() {
  asm volatile("s_waitcnt lgkmcnt(0)\n\ts_barrier" ::: "memory");
}
__device__ __forceinline__ bf16x8 pack8(float4 a, float4 b) {
  bf16x8 t;
  t[0] = (__bf16)a.x; t[1] = (__bf16)a.y; t[2] = (__bf16)a.z; t[3] = (__bf16)a.w;
  t[4] = (__bf16)b.x; t[5] = (__bf16)b.y; t[6] = (__bf16)b.z; t[7] = (__bf16)b.w;
  return t;
}
// XOR-swizzled byte offset within a [16 row][256 B] LDS tile
__device__ __forceinline__ int swz(int row, int bytecol) {
  return row * 256 + (bytecol ^ ((row & 7) << 4));
}

// ---------------------------------------------------------------------------
// Pass 1: x-projections, coop-LDS-staged. grid = 64 bblk * 8 tchunks, 256 thr.
// ---------------------------------------------------------------------------
__global__ __launch_bounds__(256, 2)
void xproj_kernel(const float* __restrict__ inputs,
                  const float* __restrict__ Wz, const float* __restrict__ bz,
                  const float* __restrict__ Wr, const float* __restrict__ br,
                  const float* __restrict__ Wh, const float* __restrict__ bh,
                  char* __restrict__ pre) {
  __shared__ __align__(16) char lds_x[2 * 4096];   // two swizzled bf16 [16][128] tiles

  const int tid  = threadIdx.x;
  const int w    = tid >> 6;
  const int l    = tid & 63;
  const int l15  = l & 15;
  const int lk   = l >> 4;
  const int bblk = blockIdx.x & (NBLK - 1);
  const int t0   = (blockIdx.x >> 6) * TCHUNK;
  const int r0   = bblk * 16;

  // coop-load role: thread -> (row, slot); loads 8 floats of x[r0+row][t*128+slot*8]
  const int crow  = tid >> 4;
  const int cslot = tid & 15;
  const float* xsrc = inputs + (size_t)(r0 + crow) * (T_N * I_DIM) + cslot * 8;
  const int cwoff = swz(crow, cslot * 16);

  // A-frags: W x-part (k=0..127). slot s: gate g=s>>1, hid0 = w*32+(s&1)*16.
  bf16x8 wb[24];
  f32x4  bias4[6];
  #pragma unroll
  for (int s = 0; s < 6; ++s) {
    int hid0 = w * 32 + (s & 1) * 16;
    const float* Wp; const float* bp;
    if (s < 2)      { Wp = Wz; bp = bz; }
    else if (s < 4) { Wp = Wr; bp = br; }
    else            { Wp = Wh; bp = bh; }
    float4 bv = *(const float4*)&bp[hid0 + lk * 4];
    bias4[s][0] = bv.x; bias4[s][1] = bv.y; bias4[s][2] = bv.z; bias4[s][3] = bv.w;
    const float* Wrow = Wp + (size_t)(hid0 + l15) * 256;
    #pragma unroll
    for (int kt = 0; kt < 4; ++kt) {
      const float* p = Wrow + kt * 32 + lk * 8;
      wb[s * 4 + kt] = pack8(*(const float4*)p, *(const float4*)(p + 4));
    }
  }

  // prologue: coop-load tile t0 into buf 0
  {
    const float* p = xsrc + (size_t)t0 * I_DIM;
    float4 a = *(const float4*)p;
    float4 b = *(const float4*)(p + 4);
    *(bf16x8*)(lds_x + cwoff) = pack8(a, b);
  }
  barrier_lds();

  #pragma unroll 2
  for (int ti = 0; ti < TCHUNK; ++ti) {
    const int t = t0 + ti;
    // issue next tile's global loads early (latency hides under MFMAs)
    float4 ra, rb2;
    if (ti + 1 < TCHUNK) {
      const float* p = xsrc + (size_t)(t + 1) * I_DIM;
      ra  = *(const float4*)p;
      rb2 = *(const float4*)(p + 4);
    }

    // frag-read current tile
    char* bufc = lds_x + ((ti & 1) ? 4096 : 0);
    bf16x8 xf[4];
    #pragma unroll
    for (int kt = 0; kt < 4; ++kt)
      xf[kt] = *(const bf16x8*)(bufc + swz(l15, kt * 64 + lk * 16));

    f32x4 acc[6];
    #pragma unroll
    for (int s = 0; s < 6; ++s) acc[s] = bias4[s];
    #pragma unroll
    for (int kt = 0; kt < 4; ++kt)
      #pragma unroll
      for (int s = 0; s < 6; ++s)
        acc[s] = __builtin_amdgcn_mfma_f32_16x16x32_bf16(wb[s * 4 + kt], xf[kt], acc[s], 0, 0, 0);

    // store coalesced: hidgrp = w*8 + (s&1)*4 + lk
    char* base = pre + ((size_t)t * NBLK + bblk) * PB_BYTES;
    #pragma unroll
    for (int s = 0; s < 6; ++s) {
      int g      = s >> 1;
      int hidgrp = w * 8 + (s & 1) * 4 + lk;
      bf16x4 v;
      v[0] = (__bf16)acc[s][0]; v[1] = (__bf16)acc[s][1];
      v[2] = (__bf16)acc[s][2]; v[3] = (__bf16)acc[s][3];
      *(bf16x4*)(base + g * GATE_BYTES + hidgrp * 128 + l15 * 8) = v;
    }

    // pack + LDS-write next tile into the other buffer
    if (ti + 1 < TCHUNK) {
      char* bufn = lds_x + (((ti + 1) & 1) ? 4096 : 0);
      *(bf16x8*)(bufn + cwoff) = pack8(ra, rb2);
    }
    barrier_lds();
  }
}

// ---------------------------------------------------------------------------
// Pass 2: recurrence — VERBATIM R9 (measured 177 us). 64 blocks, 512 threads.
// ---------------------------------------------------------------------------
__global__ __launch_bounds__(512, 1)
void augru_rec_kernel(const char* __restrict__ pre,
                      const float* __restrict__ attn,
                      const float* __restrict__ Wz,
                      const float* __restrict__ Wr,
                      const float* __restrict__ Wh,
                      float* __restrict__ out) {
  __shared__ __align__(16) short lds_h [16 * 128];  // hT  [batch][hid], swizzled
  __shared__ __align__(16) short lds_rh[16 * 128];  // rhT [batch][hid], swizzled
  __shared__ float lds_att[T_N * 16];               // [t][batch]

  const int tid   = threadIdx.x;
  const int w     = tid >> 6;
  const int l     = tid & 63;
  const int l15   = l & 15;          // batch lane
  const int lk    = l >> 4;
  const int r0    = blockIdx.x * 16;
  const int myhid = w * 16 + lk * 4; // thread's 4 contiguous hidden rows

  for (int idx = tid; idx < T_N * 16; idx += 512) {
    int t = idx >> 4, b = idx & 15;
    lds_att[idx] = attn[(size_t)(r0 + b) * T_N + t];
  }
  for (int idx = tid; idx < 16 * 128; idx += 512) lds_h[idx] = 0;

  bf16x8 wzH[4], wrH[4], whH[4];
  {
    const float* pz = Wz + (size_t)(w * 16 + l15) * 256 + 128;
    const float* pr = Wr + (size_t)(w * 16 + l15) * 256 + 128;
    const float* ph = Wh + (size_t)(w * 16 + l15) * 256 + 128;
    #pragma unroll
    for (int kt = 0; kt < 4; ++kt) {
      const float* a = pz + kt * 32 + lk * 8;
      wzH[kt] = pack8(*(const float4*)a, *(const float4*)(a + 4));
      const float* b = pr + kt * 32 + lk * 8;
      wrH[kt] = pack8(*(const float4*)b, *(const float4*)(b + 4));
      const float* cc = ph + kt * 32 + lk * 8;
      whH[kt] = pack8(*(const float4*)cc, *(const float4*)(cc + 4));
    }
  }

  float hreg[4];
  #pragma unroll
  for (int q = 0; q < 4; ++q) hreg[q] = 0.0f;

  const char* pb = pre + (size_t)blockIdx.x * PB_BYTES + (w * 4 + lk) * 128 + l15 * 8;
  const size_t tstride = (size_t)NBLK * PB_BYTES;
  bf16x4 pf[2][3];
  #pragma unroll
  for (int d = 0; d < 2; ++d)
    #pragma unroll
    for (int g = 0; g < 3; ++g)
      pf[d][g] = *(const bf16x4*)(pb + d * tstride + g * GATE_BYTES);

  const int wr_off = swz(l15, 32 * w + 8 * lk);

  __syncthreads();

  #pragma unroll 2
  for (int t = 0; t < T_N; ++t) {
    float pzv[4], prv[4], phv[4];
    #pragma unroll
    for (int q = 0; q < 4; ++q) {
      pzv[q] = (float)pf[t & 1][0][q];
      prv[q] = (float)pf[t & 1][1][q];
      phv[q] = (float)pf[t & 1][2][q];
    }
    if (t + 2 < T_N) {
      const char* b = pb + (size_t)(t + 2) * tstride;
      #pragma unroll
      for (int g = 0; g < 3; ++g)
        pf[t & 1][g] = *(const bf16x4*)(b + g * GATE_BYTES);
    }

    bf16x8 hb[4];
    #pragma unroll
    for (int kt = 0; kt < 4; ++kt)
      hb[kt] = *(const bf16x8*)((const char*)lds_h + swz(l15, kt * 64 + lk * 16));
    const float av = lds_att[t * 16 + l15];

    f32x4 zA, zB, rA, rB;
    { f32x4 a; a[0]=pzv[0]; a[1]=pzv[1]; a[2]=pzv[2]; a[3]=pzv[3]; zA = a; }
    { f32x4 a; a[0]=prv[0]; a[1]=prv[1]; a[2]=prv[2]; a[3]=prv[3]; rA = a; }
    { f32x4 z; z[0]=0.f; z[1]=0.f; z[2]=0.f; z[3]=0.f; zB = z; rB = z; }
    zA = __builtin_amdgcn_mfma_f32_16x16x32_bf16(wzH[0], hb[0], zA, 0, 0, 0);
    rA = __builtin_amdgcn_mfma_f32_16x16x32_bf16(wrH[0], hb[0], rA, 0, 0, 0);
    zB = __builtin_amdgcn_mfma_f32_16x16x32_bf16(wzH[1], hb[1], zB, 0, 0, 0);
    rB = __builtin_amdgcn_mfma_f32_16x16x32_bf16(wrH[1], hb[1], rB, 0, 0, 0);
    zA = __builtin_amdgcn_mfma_f32_16x16x32_bf16(wzH[2], hb[2], zA, 0, 0, 0);
    rA = __builtin_amdgcn_mfma_f32_16x16x32_bf16(wrH[2], hb[2], rA, 0, 0, 0);
    zB = __builtin_amdgcn_mfma_f32_16x16x32_bf16(wzH[3], hb[3], zB, 0, 0, 0);
    rB = __builtin_amdgcn_mfma_f32_16x16x32_bf16(wrH[3], hb[3], rB, 0, 0, 0);

    bf16x4 rhv;
    #pragma unroll
    for (int q = 0; q < 4; ++q) {
      float rr = fast_sigmoid(rA[q] + rB[q]);
      rhv[q] = (__bf16)(rr * hreg[q]);
    }
    *(bf16x4*)((char*)lds_rh + wr_off) = rhv;
    float zp[4];
    #pragma unroll
    for (int q = 0; q < 4; ++q)
      zp[q] = av * fast_sigmoid(zA[q] + zB[q]);
    barrier_lds();

    bf16x8 rb[4];
    #pragma unroll
    for (int kt = 0; kt < 4; ++kt)
      rb[kt] = *(const bf16x8*)((const char*)lds_rh + swz(l15, kt * 64 + lk * 16));
    f32x4 hA, hB;
    { f32x4 a; a[0]=phv[0]; a[1]=phv[1]; a[2]=phv[2]; a[3]=phv[3]; hA = a; }
    { f32x4 z; z[0]=0.f; z[1]=0.f; z[2]=0.f; z[3]=0.f; hB = z; }
    hA = __builtin_amdgcn_mfma_f32_16x16x32_bf16(whH[0], rb[0], hA, 0, 0, 0);
    hB = __builtin_amdgcn_mfma_f32_16x16x32_bf16(whH[1], rb[1], hB, 0, 0, 0);
    hA = __builtin_amdgcn_mfma_f32_16x16x32_bf16(whH[2], rb[2], hA, 0, 0, 0);
    hB = __builtin_amdgcn_mfma_f32_16x16x32_bf16(whH[3], rb[3], hB, 0, 0, 0);

    bf16x4 hbv;
    #pragma unroll
    for (int q = 0; q < 4; ++q) {
      float ht = fast_tanh(hA[q] + hB[q]);
      float hn = __builtin_fmaf(zp[q], ht - hreg[q], hreg[q]);
      hreg[q] = hn;
      hbv[q] = (__bf16)hn;
    }
    *(bf16x4*)((char*)lds_h + wr_off) = hbv;
    barrier_lds();
  }

  float4 o;
  o.x = hreg[0]; o.y = hreg[1]; o.z = hreg[2]; o.w = hreg[3];
  *(float4*)&out[(size_t)(r0 + l15) * H_DIM + myhid] = o;
}

// ---------------------------------------------------------------------------
// Fallback: proven single-kernel version (round 2, 410 us).
// ---------------------------------------------------------------------------
__global__ __launch_bounds__(256, 1)
void augru_kernel(const float* __restrict__ inputs,
                  const float* __restrict__ attn,
                  const float* __restrict__ Wz, const float* __restrict__ bz,
                  const float* __restrict__ Wr, const float* __restrict__ br,
                  const float* __restrict__ Wh, const float* __restrict__ bh,
                  float* __restrict__ out) {
  __shared__ __align__(16) short lds_a[16 * LDA_STRIDE];
  __shared__ float lds_att[16 * LATT_STRIDE];

  const int tid = threadIdx.x;
  const int w   = tid >> 6;
  const int l   = tid & 63;
  const int l15 = l & 15;
  const int lk  = l >> 4;
  const int r0  = blockIdx.x * 16;

  for (int idx = tid; idx < 16 * T_N; idx += 256) {
    int row = idx / T_N, t = idx - row * T_N;
    lds_att[row * LATT_STRIDE + t] = attn[(size_t)(r0 + row) * T_N + t];
  }
  for (int idx = tid; idx < 16 * H_DIM; idx += 256) {
    int row = idx >> 7, c = idx & 127;
    lds_a[row * LDA_STRIDE + c] = 0;
  }

  bf16x8 w1[32];
  float  bias1[4];
  #pragma unroll
  for (int ct = 0; ct < 4; ++ct) {
    int n = w * 32 + (ct & 1) * 16 + l15;
    const float* Wp; float bv;
    if (ct < 2) { Wp = Wz + (size_t)n * 256; bv = bz[n]; }
    else        { Wp = Wr + (size_t)n * 256; bv = br[n]; }
    bias1[ct] = bv;
    #pragma unroll
    for (int kt = 0; kt < 8; ++kt) {
      const float* p = Wp + kt * 32 + lk * 8;
      w1[ct * 8 + kt] = pack8(*(const float4*)p, *(const float4*)(p + 4));
    }
  }
  bf16x8 w2[16];
  float  bias2[2];
  #pragma unroll
  for (int ct = 0; ct < 2; ++ct) {
    int n = w * 32 + ct * 16 + l15;
    bias2[ct] = bh[n];
    const float* Wp = Wh + (size_t)n * 256;
    #pragma unroll
    for (int kt = 0; kt < 8; ++kt) {
      const float* p = Wp + kt * 32 + lk * 8;
      w2[ct * 8 + kt] = pack8(*(const float4*)p, *(const float4*)(p + 4));
    }
  }

  float hreg[2][4];
  #pragma unroll
  for (int ct = 0; ct < 2; ++ct)
    #pragma unroll
    for (int q = 0; q < 4; ++q) hreg[ct][q] = 0.0f;

  const float* xbase = inputs + (size_t)(r0 + l15) * (T_N * I_DIM);
  bf16x8 xfrag[4];
  #pragma unroll
  for (int kt = 0; kt < 4; ++kt) {
    const float* p = xbase + kt * 32 + lk * 8;
    xfrag[kt] = pack8(*(const float4*)p, *(const float4*)(p + 4));
  }

  __syncthreads();

  float4 xr0[4], xr1[4];
  for (int t = 0; t < T_N; ++t) {
    if (t + 1 < T_N) {
      #pragma unroll
      for (int kt = 0; kt < 4; ++kt) {
        const float* p = xbase + (size_t)(t + 1) * I_DIM + kt * 32 + lk * 8;
        xr0[kt] = *(const float4*)p;
        xr1[kt] = *(const float4*)(p + 4);
      }
    }
    bf16x8 hfrag[4];
    #pragma unroll
    for (int kt = 0; kt < 4; ++kt)
      hfrag[kt] = *(const bf16x8*)&lds_a[l15 * LDA_STRIDE + kt * 32 + lk * 8];
    float av[4];
    #pragma unroll
    for (int q = 0; q < 4; ++q) av[q] = lds_att[(lk * 4 + q) * LATT_STRIDE + t];

    f32x4 acc[4];
    #pragma unroll
    for (int ct = 0; ct < 4; ++ct) {
      f32x4 a; a[0] = bias1[ct]; a[1] = bias1[ct]; a[2] = bias1[ct]; a[3] = bias1[ct];
      acc[ct] = a;
    }
    #pragma unroll
    for (int kt = 0; kt < 4; ++kt)
      #pragma unroll
      for (int ct = 0; ct < 4; ++ct)
        acc[ct] = __builtin_amdgcn_mfma_f32_16x16x32_bf16(xfrag[kt], w1[ct * 8 + kt], acc[ct], 0, 0, 0);

    f32x4 acc2[2];
    #pragma unroll
    for (int ct = 0; ct < 2; ++ct) {
      f32x4 a; a[0] = bias2[ct]; a[1] = bias2[ct]; a[2] = bias2[ct]; a[3] = bias2[ct];
      acc2[ct] = a;
    }
    #pragma unroll
    for (int kt = 0; kt < 4; ++kt)
      #pragma unroll
      for (int ct = 0; ct < 2; ++ct)
        acc2[ct] = __builtin_amdgcn_mfma_f32_16x16x32_bf16(xfrag[kt], w2[ct * 8 + kt], acc2[ct], 0, 0, 0);

    #pragma unroll
    for (int kt = 0; kt < 4; ++kt)
      #pragma unroll
      for (int ct = 0; ct < 4; ++ct)
        acc[ct] = __builtin_amdgcn_mfma_f32_16x16x32_bf16(hfrag[kt], w1[ct * 8 + 4 + kt], acc[ct], 0, 0, 0);

    float zp[2][4];
    #pragma unroll
    for (int ct = 0; ct < 2; ++ct) {
      int col = w * 32 + ct * 16 + l15;
      #pragma unroll
      for (int q = 0; q < 4; ++q) {
        int row = lk * 4 + q;
        zp[ct][q] = av[q] * fast_sigmoid(acc[ct][q]);
        float rr = fast_sigmoid(acc[2 + ct][q]);
        __bf16 rhb = (__bf16)(rr * hreg[ct][q]);
        lds_a[row * LDA_STRIDE + 128 + col] = __builtin_bit_cast(short, rhb);
      }
    }
    barrier_lds();

    bf16x8 rfrag[4];
    #pragma unroll
    for (int kt = 0; kt < 4; ++kt)
      rfrag[kt] = *(const bf16x8*)&lds_a[l15 * LDA_STRIDE + 128 + kt * 32 + lk * 8];
    #pragma unroll
    for (int kt = 0; kt < 4; ++kt)
      #pragma unroll
      for (int ct = 0; ct < 2; ++ct)
        acc2[ct] = __builtin_amdgcn_mfma_f32_16x16x32_bf16(rfrag[kt], w2[ct * 8 + 4 + kt], acc2[ct], 0, 0, 0);

    if (t + 1 < T_N) {
      #pragma unroll
      for (int kt = 0; kt < 4; ++kt)
        xfrag[kt] = pack8(xr0[kt], xr1[kt]);
    }

    #pragma unroll
    for (int ct = 0; ct < 2; ++ct) {
      int col = w * 32 + ct * 16 + l15;
      #pragma unroll
      for (int q = 0; q < 4; ++q) {
        int row = lk * 4 + q;
        float ht = fast_tanh(acc2[ct][q]);
        float ho = hreg[ct][q];
        float hn = __builtin_fmaf(zp[ct][q], ht - ho, ho);
        hreg[ct][q] = hn;
        __bf16 hb = (__bf16)hn;
        lds_a[row * LDA_STRIDE + col] = __builtin_bit_cast(short, hb);
      }
    }
    barrier_lds();
  }

  #pragma unroll
  for (int ct = 0; ct < 2; ++ct) {
    int col = w * 32 + ct * 16 + l15;
    #pragma unroll
    for (int q = 0; q < 4; ++q) {
      int row = lk * 4 + q;
      out[(size_t)(r0 + row) * H_DIM + col] = hreg[ct][q];
    }
  }
}

extern "C" void kernel_launch(void* const* d_in, const int* in_sizes, int n_in,
                              void* d_out, int out_size, void* d_ws, size_t ws_size,
                              hipStream_t stream) {
  (void)in_sizes; (void)n_in; (void)out_size;
  const float* inputs = (const float*)d_in[0];
  const float* attn   = (const float*)d_in[1];
  const float* Wz     = (const float*)d_in[2];
  const float* bz     = (const float*)d_in[3];
  const float* Wr     = (const float*)d_in[4];
  const float* br     = (const float*)d_in[5];
  const float* Wh     = (const float*)d_in[6];
  const float* bh     = (const float*)d_in[7];
  float* out = (float*)d_out;

  if (ws_size >= PRE_BYTES) {
    char* pre = (char*)d_ws;
    xproj_kernel<<<NBLK * (T_N / TCHUNK), 256, 0, stream>>>(inputs, Wz, bz, Wr, br, Wh, bh, pre);
    augru_rec_kernel<<<NBLK, 512, 0, stream>>>(pre, attn, Wz, Wr, Wh, out);
  } else {
    augru_kernel<<<NBLK, 256, 0, stream>>>(inputs, attn, Wz, bz, Wr, br, Wh, bh, out);
  }
}

// Round 13
// 230.275 us; speedup vs baseline: 1.7646x; 1.0250x over previous
//
#include <hip/hip_runtime.h>

// AUGRU, round 13: rec spread over 256 CUs (4 batch rows/block), xproj from R12.
//  Pass 1 (xproj): VERBATIM R12 (measured ~59 us): coop-LDS-staged, coalesced.
//  Pass 2 (rec): 256 blocks x 512 thr, 4 batch rows each; 86KB LDS pad forces
//     1 block/CU -> full-chip spread. Per-CU VALU/trans per step drops 4x;
//     MFMA per block invariant (96 issues). Lanes l15>=4 duplicate lanes l&3
//     (clamped preact reads) and skip writes; LDS h rows 4..15 stay zero.
// Fallback: proven single-kernel (R2) if ws too small.

#define T_N   200
#define I_DIM 128
#define H_DIM 128
#define NBLK  64          // xproj batch tiles (16 rows)
#define NRBLK 256         // rec blocks (4 rows)
#define TCHUNK 25

typedef float  f32x4  __attribute__((ext_vector_type(4)));
typedef __bf16 bf16x4 __attribute__((ext_vector_type(4)));
typedef __bf16 bf16x8 __attribute__((ext_vector_type(8)));

// preact layout: ((t*NBLK+bblk)*3 + g)*4096 + hidgrp*128 + b*8
#define GATE_BYTES 4096
#define PB_BYTES   (3 * GATE_BYTES)
#define PRE_BYTES  ((size_t)T_N * NBLK * PB_BYTES)   // 157,286,400

// fallback LDS
#define LDA_STRIDE 264
#define LATT_STRIDE 201

__device__ __forceinline__ float fast_sigmoid(float x) {
  float e = __builtin_amdgcn_exp2f(-1.4426950408889634f * x);
  return __builtin_amdgcn_rcpf(1.0f + e);
}
__device__ __forceinline__ float fast_tanh(float x) {
  float e = __builtin_amdgcn_exp2f(2.8853900817779268f * x);
  return 1.0f - 2.0f * __builtin_amdgcn_rcpf(1.0f + e);
}
__device__ __forceinline__ void barrier_lds() {
  asm volatile("s_waitcnt lgkmcnt(0)\n\ts_barrier" ::: "memory");
}
__device__ __forceinline__ bf16x8 pack8(float4 a, float4 b) {
  bf16x8 t;
  t[0] = (__bf16)a.x; t[1] = (__bf16)a.y; t[2] = (__bf16)a.z; t[3] = (__bf16)a.w;
  t[4] = (__bf16)b.x; t[5] = (__bf16)b.y; t[6] = (__bf16)b.z; t[7] = (__bf16)b.w;
  return t;
}
// XOR-swizzled byte offset within a [16 row][256 B] LDS tile
__device__ __forceinline__ int swz(int row, int bytecol) {
  return row * 256 + (bytecol ^ ((row & 7) << 4));
}

// ---------------------------------------------------------------------------
// Pass 1: x-projections, coop-LDS-staged (VERBATIM R12). 512 blocks, 256 thr.
// ---------------------------------------------------------------------------
__global__ __launch_bounds__(256, 2)
void xproj_kernel(const float* __restrict__ inputs,
                  const float* __restrict__ Wz, const float* __restrict__ bz,
                  const float* __restrict__ Wr, const float* __restrict__ br,
                  const float* __restrict__ Wh, const float* __restrict__ bh,
                  char* __restrict__ pre) {
  __shared__ __align__(16) char lds_x[2 * 4096];

  const int tid  = threadIdx.x;
  const int w    = tid >> 6;
  const int l    = tid & 63;
  const int l15  = l & 15;
  const int lk   = l >> 4;
  const int bblk = blockIdx.x & (NBLK - 1);
  const int t0   = (blockIdx.x >> 6) * TCHUNK;
  const int r0   = bblk * 16;

  const int crow  = tid >> 4;
  const int cslot = tid & 15;
  const float* xsrc = inputs + (size_t)(r0 + crow) * (T_N * I_DIM) + cslot * 8;
  const int cwoff = swz(crow, cslot * 16);

  bf16x8 wb[24];
  f32x4  bias4[6];
  #pragma unroll
  for (int s = 0; s < 6; ++s) {
    int hid0 = w * 32 + (s & 1) * 16;
    const float* Wp; const float* bp;
    if (s < 2)      { Wp = Wz; bp = bz; }
    else if (s < 4) { Wp = Wr; bp = br; }
    else            { Wp = Wh; bp = bh; }
    float4 bv = *(const float4*)&bp[hid0 + lk * 4];
    bias4[s][0] = bv.x; bias4[s][1] = bv.y; bias4[s][2] = bv.z; bias4[s][3] = bv.w;
    const float* Wrow = Wp + (size_t)(hid0 + l15) * 256;
    #pragma unroll
    for (int kt = 0; kt < 4; ++kt) {
      const float* p = Wrow + kt * 32 + lk * 8;
      wb[s * 4 + kt] = pack8(*(const float4*)p, *(const float4*)(p + 4));
    }
  }

  {
    const float* p = xsrc + (size_t)t0 * I_DIM;
    float4 a = *(const float4*)p;
    float4 b = *(const float4*)(p + 4);
    *(bf16x8*)(lds_x + cwoff) = pack8(a, b);
  }
  barrier_lds();

  #pragma unroll 2
  for (int ti = 0; ti < TCHUNK; ++ti) {
    const int t = t0 + ti;
    float4 ra, rb2;
    if (ti + 1 < TCHUNK) {
      const float* p = xsrc + (size_t)(t + 1) * I_DIM;
      ra  = *(const float4*)p;
      rb2 = *(const float4*)(p + 4);
    }

    char* bufc = lds_x + ((ti & 1) ? 4096 : 0);
    bf16x8 xf[4];
    #pragma unroll
    for (int kt = 0; kt < 4; ++kt)
      xf[kt] = *(const bf16x8*)(bufc + swz(l15, kt * 64 + lk * 16));

    f32x4 acc[6];
    #pragma unroll
    for (int s = 0; s < 6; ++s) acc[s] = bias4[s];
    #pragma unroll
    for (int kt = 0; kt < 4; ++kt)
      #pragma unroll
      for (int s = 0; s < 6; ++s)
        acc[s] = __builtin_amdgcn_mfma_f32_16x16x32_bf16(wb[s * 4 + kt], xf[kt], acc[s], 0, 0, 0);

    char* base = pre + ((size_t)t * NBLK + bblk) * PB_BYTES;
    #pragma unroll
    for (int s = 0; s < 6; ++s) {
      int g      = s >> 1;
      int hidgrp = w * 8 + (s & 1) * 4 + lk;
      bf16x4 v;
      v[0] = (__bf16)acc[s][0]; v[1] = (__bf16)acc[s][1];
      v[2] = (__bf16)acc[s][2]; v[3] = (__bf16)acc[s][3];
      *(bf16x4*)(base + g * GATE_BYTES + hidgrp * 128 + l15 * 8) = v;
    }

    if (ti + 1 < TCHUNK) {
      char* bufn = lds_x + (((ti + 1) & 1) ? 4096 : 0);
      *(bf16x8*)(bufn + cwoff) = pack8(ra, rb2);
    }
    barrier_lds();
  }
}

// ---------------------------------------------------------------------------
// Pass 2: recurrence, 256 blocks x 4 batch rows, 512 threads.
// ---------------------------------------------------------------------------
__global__ __launch_bounds__(512, 1)
void augru_rec_kernel(const char* __restrict__ pre,
                      const float* __restrict__ attn,
                      const float* __restrict__ Wz,
                      const float* __restrict__ Wr,
                      const float* __restrict__ Wh,
                      float* __restrict__ out) {
  // 86KB pad forces 1 block/CU -> 256 blocks spread over 256 CUs.
  __shared__ __align__(16) char lds_all[86016];
  short* lds_h   = (short*)lds_all;            // [16][128] bf16, swizzled; rows 4-15 zero
  short* lds_rh  = (short*)(lds_all + 4096);   // [16][128] bf16, swizzled
  float* lds_att = (float*)(lds_all + 8192);   // [t][4]

  const int tid   = threadIdx.x;
  const int w     = tid >> 6;
  const int l     = tid & 63;
  const int l15   = l & 15;          // batch lane (0..3 real)
  const int l3    = l & 3;           // clamped batch lane
  const int lk    = l >> 4;
  const int rb    = blockIdx.x;
  const int bblk  = rb >> 2;         // 16-row xproj tile
  const int sb    = (rb & 3) * 4;    // sub-batch offset within tile
  const int r0    = rb * 4;          // global batch base (= bblk*16 + sb)
  const int myhid = w * 16 + lk * 4;
  const bool wr_ok = (l15 < 4);

  // ---- prologue ----
  for (int idx = tid; idx < T_N * 4; idx += 512) {
    int t = idx >> 2, b = idx & 3;
    lds_att[idx] = attn[(size_t)(r0 + b) * T_N + t];
  }
  for (int idx = tid; idx < 16 * 128; idx += 512) lds_h[idx] = 0;

  // ---- A-frags: recurrent weights (k=128..255), rows = hidden w*16+l15 ----
  bf16x8 wzH[4], wrH[4], whH[4];
  {
    const float* pz = Wz + (size_t)(w * 16 + l15) * 256 + 128;
    const float* pr = Wr + (size_t)(w * 16 + l15) * 256 + 128;
    const float* ph = Wh + (size_t)(w * 16 + l15) * 256 + 128;
    #pragma unroll
    for (int kt = 0; kt < 4; ++kt) {
      const float* a = pz + kt * 32 + lk * 8;
      wzH[kt] = pack8(*(const float4*)a, *(const float4*)(a + 4));
      const float* b = pr + kt * 32 + lk * 8;
      wrH[kt] = pack8(*(const float4*)b, *(const float4*)(b + 4));
      const float* cc = ph + kt * 32 + lk * 8;
      whH[kt] = pack8(*(const float4*)cc, *(const float4*)(cc + 4));
    }
  }

  float hreg[4];
  #pragma unroll
  for (int q = 0; q < 4; ++q) hreg[q] = 0.0f;

  // ---- preact ring (depth 2). Lanes l15>=4 duplicate lane l&3 (clamped). ----
  const char* pb = pre + (size_t)bblk * PB_BYTES + (w * 4 + lk) * 128 + (sb + l3) * 8;
  const size_t tstride = (size_t)NBLK * PB_BYTES;
  bf16x4 pf[2][3];
  #pragma unroll
  for (int d = 0; d < 2; ++d)
    #pragma unroll
    for (int g = 0; g < 3; ++g)
      pf[d][g] = *(const bf16x4*)(pb + d * tstride + g * GATE_BYTES);

  const int wr_off = swz(l15, 32 * w + 8 * lk);

  __syncthreads();

  #pragma unroll 2
  for (int t = 0; t < T_N; ++t) {
    float pzv[4], prv[4], phv[4];
    #pragma unroll
    for (int q = 0; q < 4; ++q) {
      pzv[q] = (float)pf[t & 1][0][q];
      prv[q] = (float)pf[t & 1][1][q];
      phv[q] = (float)pf[t & 1][2][q];
    }
    if (t + 2 < T_N) {
      const char* b = pb + (size_t)(t + 2) * tstride;
      #pragma unroll
      for (int g = 0; g < 3; ++g)
        pf[t & 1][g] = *(const bf16x4*)(b + g * GATE_BYTES);
    }

    bf16x8 hb[4];
    #pragma unroll
    for (int kt = 0; kt < 4; ++kt)
      hb[kt] = *(const bf16x8*)((const char*)lds_h + swz(l15, kt * 64 + lk * 16));
    const float av = lds_att[t * 4 + l3];

    f32x4 zA, zB, rA, rB;
    { f32x4 a; a[0]=pzv[0]; a[1]=pzv[1]; a[2]=pzv[2]; a[3]=pzv[3]; zA = a; }
    { f32x4 a; a[0]=prv[0]; a[1]=prv[1]; a[2]=prv[2]; a[3]=prv[3]; rA = a; }
    { f32x4 z; z[0]=0.f; z[1]=0.f; z[2]=0.f; z[3]=0.f; zB = z; rB = z; }
    zA = __builtin_amdgcn_mfma_f32_16x16x32_bf16(wzH[0], hb[0], zA, 0, 0, 0);
    rA = __builtin_amdgcn_mfma_f32_16x16x32_bf16(wrH[0], hb[0], rA, 0, 0, 0);
    zB = __builtin_amdgcn_mfma_f32_16x16x32_bf16(wzH[1], hb[1], zB, 0, 0, 0);
    rB = __builtin_amdgcn_mfma_f32_16x16x32_bf16(wrH[1], hb[1], rB, 0, 0, 0);
    zA = __builtin_amdgcn_mfma_f32_16x16x32_bf16(wzH[2], hb[2], zA, 0, 0, 0);
    rA = __builtin_amdgcn_mfma_f32_16x16x32_bf16(wrH[2], hb[2], rA, 0, 0, 0);
    zB = __builtin_amdgcn_mfma_f32_16x16x32_bf16(wzH[3], hb[3], zB, 0, 0, 0);
    rB = __builtin_amdgcn_mfma_f32_16x16x32_bf16(wrH[3], hb[3], rB, 0, 0, 0);

    bf16x4 rhv;
    #pragma unroll
    for (int q = 0; q < 4; ++q) {
      float rr = fast_sigmoid(rA[q] + rB[q]);
      rhv[q] = (__bf16)(rr * hreg[q]);
    }
    if (wr_ok) *(bf16x4*)((char*)lds_rh + wr_off) = rhv;
    float zp[4];
    #pragma unroll
    for (int q = 0; q < 4; ++q)
      zp[q] = av * fast_sigmoid(zA[q] + zB[q]);
    barrier_lds();

    bf16x8 rb4[4];
    #pragma unroll
    for (int kt = 0; kt < 4; ++kt)
      rb4[kt] = *(const bf16x8*)((const char*)lds_rh + swz(l15, kt * 64 + lk * 16));
    f32x4 hA, hB;
    { f32x4 a; a[0]=phv[0]; a[1]=phv[1]; a[2]=phv[2]; a[3]=phv[3]; hA = a; }
    { f32x4 z; z[0]=0.f; z[1]=0.f; z[2]=0.f; z[3]=0.f; hB = z; }
    hA = __builtin_amdgcn_mfma_f32_16x16x32_bf16(whH[0], rb4[0], hA, 0, 0, 0);
    hB = __builtin_amdgcn_mfma_f32_16x16x32_bf16(whH[1], rb4[1], hB, 0, 0, 0);
    hA = __builtin_amdgcn_mfma_f32_16x16x32_bf16(whH[2], rb4[2], hA, 0, 0, 0);
    hB = __builtin_amdgcn_mfma_f32_16x16x32_bf16(whH[3], rb4[3], hB, 0, 0, 0);

    bf16x4 hbv;
    #pragma unroll
    for (int q = 0; q < 4; ++q) {
      float ht = fast_tanh(hA[q] + hB[q]);
      float hn = __builtin_fmaf(zp[q], ht - hreg[q], hreg[q]);
      hreg[q] = hn;
      hbv[q] = (__bf16)hn;
    }
    if (wr_ok) *(bf16x4*)((char*)lds_h + wr_off) = hbv;
    barrier_lds();
  }

  if (wr_ok) {
    float4 o;
    o.x = hreg[0]; o.y = hreg[1]; o.z = hreg[2]; o.w = hreg[3];
    *(float4*)&out[(size_t)(r0 + l15) * H_DIM + myhid] = o;
  }
}

// ---------------------------------------------------------------------------
// Fallback: proven single-kernel version (round 2, 410 us).
// ---------------------------------------------------------------------------
__global__ __launch_bounds__(256, 1)
void augru_kernel(const float* __restrict__ inputs,
                  const float* __restrict__ attn,
                  const float* __restrict__ Wz, const float* __restrict__ bz,
                  const float* __restrict__ Wr, const float* __restrict__ br,
                  const float* __restrict__ Wh, const float* __restrict__ bh,
                  float* __restrict__ out) {
  __shared__ __align__(16) short lds_a[16 * LDA_STRIDE];
  __shared__ float lds_att[16 * LATT_STRIDE];

  const int tid = threadIdx.x;
  const int w   = tid >> 6;
  const int l   = tid & 63;
  const int l15 = l & 15;
  const int lk  = l >> 4;
  const int r0  = blockIdx.x * 16;

  for (int idx = tid; idx < 16 * T_N; idx += 256) {
    int row = idx / T_N, t = idx - row * T_N;
    lds_att[row * LATT_STRIDE + t] = attn[(size_t)(r0 + row) * T_N + t];
  }
  for (int idx = tid; idx < 16 * H_DIM; idx += 256) {
    int row = idx >> 7, c = idx & 127;
    lds_a[row * LDA_STRIDE + c] = 0;
  }

  bf16x8 w1[32];
  float  bias1[4];
  #pragma unroll
  for (int ct = 0; ct < 4; ++ct) {
    int n = w * 32 + (ct & 1) * 16 + l15;
    const float* Wp; float bv;
    if (ct < 2) { Wp = Wz + (size_t)n * 256; bv = bz[n]; }
    else        { Wp = Wr + (size_t)n * 256; bv = br[n]; }
    bias1[ct] = bv;
    #pragma unroll
    for (int kt = 0; kt < 8; ++kt) {
      const float* p = Wp + kt * 32 + lk * 8;
      w1[ct * 8 + kt] = pack8(*(const float4*)p, *(const float4*)(p + 4));
    }
  }
  bf16x8 w2[16];
  float  bias2[2];
  #pragma unroll
  for (int ct = 0; ct < 2; ++ct) {
    int n = w * 32 + ct * 16 + l15;
    bias2[ct] = bh[n];
    const float* Wp = Wh + (size_t)n * 256;
    #pragma unroll
    for (int kt = 0; kt < 8; ++kt) {
      const float* p = Wp + kt * 32 + lk * 8;
      w2[ct * 8 + kt] = pack8(*(const float4*)p, *(const float4*)(p + 4));
    }
  }

  float hreg[2][4];
  #pragma unroll
  for (int ct = 0; ct < 2; ++ct)
    #pragma unroll
    for (int q = 0; q < 4; ++q) hreg[ct][q] = 0.0f;

  const float* xbase = inputs + (size_t)(r0 + l15) * (T_N * I_DIM);
  bf16x8 xfrag[4];
  #pragma unroll
  for (int kt = 0; kt < 4; ++kt) {
    const float* p = xbase + kt * 32 + lk * 8;
    xfrag[kt] = pack8(*(const float4*)p, *(const float4*)(p + 4));
  }

  __syncthreads();

  float4 xr0[4], xr1[4];
  for (int t = 0; t < T_N; ++t) {
    if (t + 1 < T_N) {
      #pragma unroll
      for (int kt = 0; kt < 4; ++kt) {
        const float* p = xbase + (size_t)(t + 1) * I_DIM + kt * 32 + lk * 8;
        xr0[kt] = *(const float4*)p;
        xr1[kt] = *(const float4*)(p + 4);
      }
    }
    bf16x8 hfrag[4];
    #pragma unroll
    for (int kt = 0; kt < 4; ++kt)
      hfrag[kt] = *(const bf16x8*)&lds_a[l15 * LDA_STRIDE + kt * 32 + lk * 8];
    float av[4];
    #pragma unroll
    for (int q = 0; q < 4; ++q) av[q] = lds_att[(lk * 4 + q) * LATT_STRIDE + t];

    f32x4 acc[4];
    #pragma unroll
    for (int ct = 0; ct < 4; ++ct) {
      f32x4 a; a[0] = bias1[ct]; a[1] = bias1[ct]; a[2] = bias1[ct]; a[3] = bias1[ct];
      acc[ct] = a;
    }
    #pragma unroll
    for (int kt = 0; kt < 4; ++kt)
      #pragma unroll
      for (int ct = 0; ct < 4; ++ct)
        acc[ct] = __builtin_amdgcn_mfma_f32_16x16x32_bf16(xfrag[kt], w1[ct * 8 + kt], acc[ct], 0, 0, 0);

    f32x4 acc2[2];
    #pragma unroll
    for (int ct = 0; ct < 2; ++ct) {
      f32x4 a; a[0] = bias2[ct]; a[1] = bias2[ct]; a[2] = bias2[ct]; a[3] = bias2[ct];
      acc2[ct] = a;
    }
    #pragma unroll
    for (int kt = 0; kt < 4; ++kt)
      #pragma unroll
      for (int ct = 0; ct < 2; ++ct)
        acc2[ct] = __builtin_amdgcn_mfma_f32_16x16x32_bf16(xfrag[kt], w2[ct * 8 + kt], acc2[ct], 0, 0, 0);

    #pragma unroll
    for (int kt = 0; kt < 4; ++kt)
      #pragma unroll
      for (int ct = 0; ct < 4; ++ct)
        acc[ct] = __builtin_amdgcn_mfma_f32_16x16x32_bf16(hfrag[kt], w1[ct * 8 + 4 + kt], acc[ct], 0, 0, 0);

    float zp[2][4];
    #pragma unroll
    for (int ct = 0; ct < 2; ++ct) {
      int col = w * 32 + ct * 16 + l15;
      #pragma unroll
      for (int q = 0; q < 4; ++q) {
        int row = lk * 4 + q;
        zp[ct][q] = av[q] * fast_sigmoid(acc[ct][q]);
        float rr = fast_sigmoid(acc[2 + ct][q]);
        __bf16 rhb = (__bf16)(rr * hreg[ct][q]);
        lds_a[row * LDA_STRIDE + 128 + col] = __builtin_bit_cast(short, rhb);
      }
    }
    barrier_lds();

    bf16x8 rfrag[4];
    #pragma unroll
    for (int kt = 0; kt < 4; ++kt)
      rfrag[kt] = *(const bf16x8*)&lds_a[l15 * LDA_STRIDE + 128 + kt * 32 + lk * 8];
    #pragma unroll
    for (int kt = 0; kt < 4; ++kt)
      #pragma unroll
      for (int ct = 0; ct < 2; ++ct)
        acc2[ct] = __builtin_amdgcn_mfma_f32_16x16x32_bf16(rfrag[kt], w2[ct * 8 + 4 + kt], acc2[ct], 0, 0, 0);

    if (t + 1 < T_N) {
      #pragma unroll
      for (int kt = 0; kt < 4; ++kt)
        xfrag[kt] = pack8(xr0[kt], xr1[kt]);
    }

    #pragma unroll
    for (int ct = 0; ct < 2; ++ct) {
      int col = w * 32 + ct * 16 + l15;
      #pragma unroll
      for (int q = 0; q < 4; ++q) {
        int row = lk * 4 + q;
        float ht = fast_tanh(acc2[ct][q]);
        float ho = hreg[ct][q];
        float hn = __builtin_fmaf(zp[ct][q], ht - ho, ho);
        hreg[ct][q] = hn;
        __bf16 hb = (__bf16)hn;
        lds_a[row * LDA_STRIDE + col] = __builtin_bit_cast(short, hb);
      }
    }
    barrier_lds();
  }

  #pragma unroll
  for (int ct = 0; ct < 2; ++ct) {
    int col = w * 32 + ct * 16 + l15;
    #pragma unroll
    for (int q = 0; q < 4; ++q) {
      int row = lk * 4 + q;
      out[(size_t)(r0 + row) * H_DIM + col] = hreg[ct][q];
    }
  }
}

extern "C" void kernel_launch(void* const* d_in, const int* in_sizes, int n_in,
                              void* d_out, int out_size, void* d_ws, size_t ws_size,
                              hipStream_t stream) {
  (void)in_sizes; (void)n_in; (void)out_size;
  const float* inputs = (const float*)d_in[0];
  const float* attn   = (const float*)d_in[1];
  const float* Wz     = (const float*)d_in[2];
  const float* bz     = (const float*)d_in[3];
  const float* Wr     = (const float*)d_in[4];
  const float* br     = (const float*)d_in[5];
  const float* Wh     = (const float*)d_in[6];
  const float* bh     = (const float*)d_in[7];
  float* out = (float*)d_out;

  if (ws_size >= PRE_BYTES) {
    char* pre = (char*)d_ws;
    xproj_kernel<<<NBLK * (T_N / TCHUNK), 256, 0, stream>>>(inputs, Wz, bz, Wr, br, Wh, bh, pre);
    augru_rec_kernel<<<NRBLK, 512, 0, stream>>>(pre, attn, Wz, Wr, Wh, out);
  } else {
    augru_kernel<<<NBLK, 256, 0, stream>>>(inputs, attn, Wz, bz, Wr, br, Wh, bh, out);
  }
}